// Round 3
// baseline (516.190 us; speedup 1.0000x reference)
//
#include <hip/hip_runtime.h>
#include <hip/hip_bf16.h>

#define DD 32   // node/output dim
#define HH 64   // psi hidden
// PSI_IN = 5*32 = 160

typedef __attribute__((ext_vector_type(8))) short bf16x8;   // 8 bf16 = 4 VGPRs
typedef __attribute__((ext_vector_type(4))) float f32x4;

static __device__ __forceinline__ unsigned short f2bf(float x) {
    union { float f; unsigned u; } v; v.f = x;
    return (unsigned short)((v.u + 0x7FFFu + ((v.u >> 16) & 1u)) >> 16);
}

// packed f32x2 -> bf16x2 (v_cvt_pk_bf16_f32), low = a
static __device__ __forceinline__ unsigned pk2(float a, float b) {
    __hip_bfloat162 h = __float22bfloat162_rn(make_float2(a, b));
    union { __hip_bfloat162 h2; unsigned u; } cv; cv.h2 = h; return cv.u;
}

// Weight fragments, TRANSPOSED layout (A-operand = W^T, M=out-features).
// A-frag 16x16x32: lane l (c=l&15,q=l>>4): m = t*16+c, k = q*8+j.
//  wf0: 20 frags (t<4, kk<5):  k_glob = kk*32 + q*8 + j          -> w0[k][m]
//  wf1:  8 frags (t<4, kp<2):  k_glob = kp*32 + (j>>2)*16 + q*4 + (j&3) -> w1[k][m]
//       (one 32-K MFMA = two independent 16-K products summed; halves j<4 / j>=4
//        carry k-tiles 2kp and 2kp+1 so B can be the concatenated C-fragments)
//  wf2:  4 frags (t<2, kp<2):  same interleave -> w2[k][m]
// Offsets in shorts: wf0 @0 (20*512), wf1 @10240 (8*512), wf2 @14336 (4*512).
__global__ __launch_bounds__(256) void prep_weights(
    const float* __restrict__ w0, const float* __restrict__ w1,
    const float* __restrict__ w2, unsigned short* __restrict__ frags)
{
    const int tid = blockIdx.x * 256 + threadIdx.x;
    const int f = tid >> 6, l = tid & 63;
    if (f >= 32) return;
    const int c = l & 15, q = l >> 4;
    unsigned short* dst = frags + f * 512 + l * 8;
    if (f < 20) {                       // wf0
        const int t = f / 5, kk = f % 5;
        const int m = t * 16 + c;
        #pragma unroll
        for (int j = 0; j < 8; ++j) {
            const int k = kk * 32 + q * 8 + j;
            dst[j] = f2bf(w0[k * HH + m]);
        }
    } else if (f < 28) {                // wf1
        const int f1 = f - 20, t = f1 >> 1, kp = f1 & 1;
        const int m = t * 16 + c;
        #pragma unroll
        for (int j = 0; j < 8; ++j) {
            const int k = kp * 32 + (j >> 2) * 16 + q * 4 + (j & 3);
            dst[j] = f2bf(w1[k * HH + m]);
        }
    } else {                            // wf2
        const int f2i = f - 28, t = f2i >> 1, kp = f2i & 1;
        const int m = t * 16 + c;
        #pragma unroll
        for (int j = 0; j < 8; ++j) {
            const int k = kp * 32 + (j >> 2) * 16 + q * 4 + (j & 3);
            dst[j] = f2bf(w2[k * DD + m]);
        }
    }
}

// One wave per 16-edge tile, transposed MLP (features on M, edges on N).
// Zero LDS. All inter-layer transforms are in-register packed bf16 converts:
// C-layout (col=edge=lane&15, row=q*4+reg) IS the next B-frag layout under the
// dual-16K interleave. Biases folded into accumulator init.
__global__ __launch_bounds__(256, 2) void edge_mfma(
    const float* __restrict__ h_d, const float* __restrict__ h_s,
    const float* __restrict__ ef,
    const int* __restrict__ snd, const int* __restrict__ rcv,
    const unsigned short* __restrict__ frags,
    const float* __restrict__ b0, const float* __restrict__ b1,
    const float* __restrict__ b2,
    float* __restrict__ agg, int E, int ntiles)
{
    const int lane = threadIdx.x & 63;
    const int c = lane & 15, q = lane >> 4;

    bf16x8 wf0[20];
    #pragma unroll
    for (int f = 0; f < 20; ++f) wf0[f] = *(const bf16x8*)(frags + f * 512 + lane * 8);
    bf16x8 wf1[8];
    #pragma unroll
    for (int f = 0; f < 8; ++f) wf1[f] = *(const bf16x8*)(frags + 10240 + f * 512 + lane * 8);
    bf16x8 wf2[4];
    #pragma unroll
    for (int f = 0; f < 4; ++f) wf2[f] = *(const bf16x8*)(frags + 14336 + f * 512 + lane * 8);

    // bias fragments: feature = t*16 + q*4 + r  -> float4 per tile t
    f32x4 b0v[4], b1v[4], b2v[2];
    #pragma unroll
    for (int t = 0; t < 4; ++t) b0v[t] = *(const f32x4*)(b0 + t * 16 + q * 4);
    #pragma unroll
    for (int t = 0; t < 4; ++t) b1v[t] = *(const f32x4*)(b1 + t * 16 + q * 4);
    #pragma unroll
    for (int t = 0; t < 2; ++t) b2v[t] = *(const f32x4*)(b2 + t * 16 + q * 4);

    const int wave_id = blockIdx.x * 4 + (threadIdx.x >> 6);
    const int nwaves = gridDim.x * 4;

    for (int tile = wave_id; tile < ntiles; tile += nwaves) {
        const int base = tile * 16;
        int e = base + c;
        const bool valid = (e < E);
        if (!valid) e = E - 1;
        const int si = snd[e], ri = rcv[e];

        const float* s0 = h_s + (size_t)si * DD;
        const float* s1 = h_s + (size_t)ri * DD;
        const float* s2 = h_d + (size_t)si * DD;   // h_di
        const float* s3 = h_d + (size_t)ri * DD;   // h_dj
        const float* s4 = ef  + (size_t)e  * DD;

        // epilogue diff gathers, issued early (same rows as layer-0 chunks 2/3)
        f32x4 di[2], dj[2];
        #pragma unroll
        for (int t = 0; t < 2; ++t) {
            di[t] = *(const f32x4*)(s2 + t * 16 + q * 4);
            dj[t] = *(const f32x4*)(s3 + t * 16 + q * 4);
        }

        // ---- layer 0: X1^T[64x16] = W0^T[64x160] @ X0^T[160x16] ----
        f32x4 c0[4] = {b0v[0], b0v[1], b0v[2], b0v[3]};
        const float* srcs[5] = {s0, s1, s2, s3, s4};
        #pragma unroll
        for (int kk = 0; kk < 5; ++kk) {
            const f32x4 u0 = *(const f32x4*)(srcs[kk] + q * 8);
            const f32x4 u1 = *(const f32x4*)(srcs[kk] + q * 8 + 4);
            union { unsigned u[4]; bf16x8 v; } bb;
            bb.u[0] = pk2(u0[0], u0[1]); bb.u[1] = pk2(u0[2], u0[3]);
            bb.u[2] = pk2(u1[0], u1[1]); bb.u[3] = pk2(u1[2], u1[3]);
            #pragma unroll
            for (int t = 0; t < 4; ++t)
                c0[t] = __builtin_amdgcn_mfma_f32_16x16x32_bf16(wf0[t * 5 + kk], bb.v, c0[t], 0, 0, 0);
        }

        // relu + pack: x1[kt] = 2 VGPRs of bf16, kt-tile of features
        unsigned x1[4][2];
        #pragma unroll
        for (int kt = 0; kt < 4; ++kt) {
            x1[kt][0] = pk2(fmaxf(c0[kt][0], 0.f), fmaxf(c0[kt][1], 0.f));
            x1[kt][1] = pk2(fmaxf(c0[kt][2], 0.f), fmaxf(c0[kt][3], 0.f));
        }

        // ---- layer 1: X2^T[64x16] = W1^T[64x64] @ X1^T[64x16], dual-16K MFMAs ----
        f32x4 c1[4] = {b1v[0], b1v[1], b1v[2], b1v[3]};
        #pragma unroll
        for (int kp = 0; kp < 2; ++kp) {
            union { unsigned u[4]; bf16x8 v; } bb;
            bb.u[0] = x1[2 * kp][0];     bb.u[1] = x1[2 * kp][1];
            bb.u[2] = x1[2 * kp + 1][0]; bb.u[3] = x1[2 * kp + 1][1];
            #pragma unroll
            for (int t = 0; t < 4; ++t)
                c1[t] = __builtin_amdgcn_mfma_f32_16x16x32_bf16(wf1[t * 2 + kp], bb.v, c1[t], 0, 0, 0);
        }

        unsigned x2[4][2];
        #pragma unroll
        for (int kt = 0; kt < 4; ++kt) {
            x2[kt][0] = pk2(fmaxf(c1[kt][0], 0.f), fmaxf(c1[kt][1], 0.f));
            x2[kt][1] = pk2(fmaxf(c1[kt][2], 0.f), fmaxf(c1[kt][3], 0.f));
        }

        // ---- layer 2: psi^T[32x16] = W2^T[32x64] @ X2^T[64x16] ----
        f32x4 c2[2] = {b2v[0], b2v[1]};
        #pragma unroll
        for (int kp = 0; kp < 2; ++kp) {
            union { unsigned u[4]; bf16x8 v; } bb;
            bb.u[0] = x2[2 * kp][0];     bb.u[1] = x2[2 * kp][1];
            bb.u[2] = x2[2 * kp + 1][0]; bb.u[3] = x2[2 * kp + 1][1];
            #pragma unroll
            for (int t = 0; t < 2; ++t)
                c2[t] = __builtin_amdgcn_mfma_f32_16x16x32_bf16(wf2[t * 2 + kp], bb.v, c2[t], 0, 0, 0);
        }

        // ---- epilogue: lane(c,q) owns edge c, features t*16+q*4+r ----
        if (valid) {
            float* ar = agg + (size_t)ri * DD + q * 4;
            #pragma unroll
            for (int t = 0; t < 2; ++t) {
                #pragma unroll
                for (int r = 0; r < 4; ++r) {
                    const float psi = fmaxf(c2[t][r], 0.f);
                    atomicAdd(ar + t * 16 + r, psi * (dj[t][r] - di[t][r]));
                }
            }
        }
    }
}

// out[n][:] = h_d_prev[n][:] + agg[n][:] @ W ; one thread per node, W wave-uniform
__global__ __launch_bounds__(256) void out_kernel(
    const float* __restrict__ h_d, const float* __restrict__ agg,
    const float* __restrict__ W, float* __restrict__ out, int N)
{
    const int n = blockIdx.x * 256 + threadIdx.x;
    if (n >= N) return;
    const f32x4* ar = (const f32x4*)(agg + (size_t)n * DD);
    const f32x4* hr = (const f32x4*)(h_d + (size_t)n * DD);
    float a[DD], o[DD];
    #pragma unroll
    for (int i = 0; i < 8; ++i) {
        const f32x4 av = ar[i], hv = hr[i];
        a[4 * i] = av[0]; a[4 * i + 1] = av[1]; a[4 * i + 2] = av[2]; a[4 * i + 3] = av[3];
        o[4 * i] = hv[0]; o[4 * i + 1] = hv[1]; o[4 * i + 2] = hv[2]; o[4 * i + 3] = hv[3];
    }
    #pragma unroll
    for (int k = 0; k < DD; ++k) {
        const float ak = a[k];
        #pragma unroll
        for (int d = 0; d < DD; ++d) o[d] = fmaf(ak, W[k * DD + d], o[d]);
    }
    f32x4* ov = (f32x4*)(out + (size_t)n * DD);
    #pragma unroll
    for (int i = 0; i < 8; ++i) ov[i] = f32x4{o[4 * i], o[4 * i + 1], o[4 * i + 2], o[4 * i + 3]};
}

extern "C" void kernel_launch(void* const* d_in, const int* in_sizes, int n_in,
                              void* d_out, int out_size, void* d_ws, size_t ws_size,
                              hipStream_t stream) {
    const float* h_d = (const float*)d_in[0];
    const float* h_s = (const float*)d_in[1];
    const float* ef  = (const float*)d_in[2];
    const int*   snd = (const int*)d_in[3];
    const int*   rcv = (const int*)d_in[4];
    const float* w0  = (const float*)d_in[5];
    const float* b0  = (const float*)d_in[6];
    const float* w1  = (const float*)d_in[7];
    const float* b1  = (const float*)d_in[8];
    const float* w2  = (const float*)d_in[9];
    const float* b2  = (const float*)d_in[10];
    const float* W   = (const float*)d_in[11];
    float* out = (float*)d_out;

    const int N = in_sizes[0] / DD;
    const int E = in_sizes[3];
    const int ntiles = (E + 15) / 16;

    // d_ws: [0, N*DD floats) = agg ; then 32 KB of bf16 weight frags
    float* agg = (float*)d_ws;
    unsigned short* frags = (unsigned short*)((char*)d_ws + (size_t)N * DD * sizeof(float));

    hipMemsetAsync(agg, 0, (size_t)N * DD * sizeof(float), stream);
    prep_weights<<<8, 256, 0, stream>>>(w0, w1, w2, frags);
    edge_mfma<<<1024, 256, 0, stream>>>(h_d, h_s, ef, snd, rcv, frags,
                                        b0, b1, b2, agg, E, ntiles);
    out_kernel<<<(N + 255) / 256, 256, 0, stream>>>(h_d, agg, W, out, N);
}